// Round 1
// 739.331 us; speedup vs baseline: 1.1767x; 1.1767x over previous
//
#include <hip/hip_runtime.h>

// PolicyHead fused kernel, R3.
// R2 post-mortem: latency-bound (MfmaUtil 7.3%, VALUBusy 7.4%, HBM 3.5%,
// Occupancy 23.5% ~= 2 blocks/CU). Stalls: per-n LDS scratch round-trips,
// 8-deep dependent MFMA chains, serial gather, low residency.
// R3 changes:
//  - LDS 54272 -> 33152 B: ks un-padded with XOR swizzle ((row&7)<<4 on byte
//    addr); fullbuf (67x64 f32 = 17152 B) ALIASED onto ks region (logits held
//    in regs until ks readers sync). __launch_bounds__(256,4) -> 4 blocks/CU.
//  - Bulk transpose: layers 1-2 write the whole 16x256 tile into the wave's
//    slice of the swizzled buffer, ONE wait, then 8x ds_read_b128 fragments
//    (replaces 16 write->wait->read round-trips per layer).
//  - Dual accumulators per n-tile (t even/odd) -> 2x MFMA ILP.
//  - Gather: batch all 8 gidx loads, then 8 LDS reads, then 8 stores.
//  - Wave 3 stages the logits[48:56,56:64] patch to a small LDS buffer so the
//    promo-row build needs no extra barrier on fullbuf.

typedef __bf16 bf16_t;
typedef __bf16 bf16x8 __attribute__((ext_vector_type(8)));
typedef float  f32x4  __attribute__((ext_vector_type(4)));

#define PSCALE 0.0625f
#define NPOL   1858

__global__ void prep_weights(const float* __restrict__ w1,
                             const float* __restrict__ w2,
                             const float* __restrict__ w3,
                             bf16_t* __restrict__ wf) {
    // wf flat layout: [which][n(16)][t(8)][lane(64)][j(8)]
    int i = blockIdx.x * 256 + threadIdx.x;      // 0 .. 3*65536-1
    int which = i >> 16;
    int r = i & 65535;
    int j    = r & 7;
    int lane = (r >> 3) & 63;
    int t    = (r >> 9) & 7;
    int n    = (r >> 12) & 15;
    const float* w = (which == 0) ? w1 : (which == 1 ? w2 : w3);
    int row = n * 16 + (lane & 15);              // output-col index (w row)
    int col = t * 32 + (lane >> 4) * 8 + j;      // k index
    wf[i] = (bf16_t)w[row * 256 + col];
}

// B-operand fragment for col-tile n, k-tile t: lane holds
// w[n*16 + (lane&15)][t*32 + (lane>>4)*8 + j], j=0..7.
template <bool USE_WS>
__device__ __forceinline__ bf16x8 wfrag(const bf16_t* __restrict__ wl,
                                        const float* __restrict__ w,
                                        int n, int t, int lane) {
    if (USE_WS) {
        return *(const bf16x8*)(wl + (((n * 8 + t) * 64 + lane) << 3));
    } else {
        int l15 = lane & 15, quad = lane >> 4;
        const float* p = w + (n * 16 + l15) * 256 + t * 32 + quad * 8;
        f32x4 lo = *(const f32x4*)p;
        f32x4 hi = *(const f32x4*)(p + 4);
        bf16x8 v;
        v[0] = (bf16_t)lo[0]; v[1] = (bf16_t)lo[1];
        v[2] = (bf16_t)lo[2]; v[3] = (bf16_t)lo[3];
        v[4] = (bf16_t)hi[0]; v[5] = (bf16_t)hi[1];
        v[6] = (bf16_t)hi[2]; v[7] = (bf16_t)hi[3];
        return v;
    }
}

// Swizzled byte offset into the 64x256 bf16 union buffer.
// b128 reads at col%8==0 stay 16B-aligned (XOR touches bits 4..6 only).
__device__ __forceinline__ int ks_off(int row, int col) {
    return ((row << 9) + (col << 1)) ^ ((row & 7) << 4);
}

template <bool USE_WS>
__device__ __forceinline__ f32x4 gemm_row16(const bf16x8* in,
                                            const bf16_t* __restrict__ wl,
                                            const float* __restrict__ wraw,
                                            int n, int lane) {
    f32x4 a0 = {0.f, 0.f, 0.f, 0.f};
    f32x4 a1 = {0.f, 0.f, 0.f, 0.f};
    #pragma unroll
    for (int t = 0; t < 8; t += 2) {
        a0 = __builtin_amdgcn_mfma_f32_16x16x32_bf16(
                 in[t],     wfrag<USE_WS>(wl, wraw, n, t,     lane), a0, 0, 0, 0);
        a1 = __builtin_amdgcn_mfma_f32_16x16x32_bf16(
                 in[t + 1], wfrag<USE_WS>(wl, wraw, n, t + 1, lane), a1, 0, 0, 0);
    }
    return a0 + a1;
}

template <bool USE_WS>
__global__ __launch_bounds__(256, 4)
void policy_main(const float* __restrict__ x,
                 const bf16_t* __restrict__ wf,   // [3][16][8][64][8] bf16
                 const float* __restrict__ w1,
                 const float* __restrict__ w2,
                 const float* __restrict__ w3,
                 const float* __restrict__ b1,
                 const float* __restrict__ b2,
                 const float* __restrict__ b3,
                 const float* __restrict__ w4,
                 const int*   __restrict__ gidx,
                 float* __restrict__ out) {
    // 32768 B union: phase A = k (64 rows x 256 bf16, XOR-swizzled);
    //                phase B = fullbuf (67x64 f32 = 17152 B, linear).
    __shared__ __align__(16) unsigned char u_lds[64 * 512];
    __shared__ float promoLDS[4][8];
    __shared__ float patchLDS[8][8];   // logits[48:56, 56:64], scaled

    const int tid  = threadIdx.x;
    const int lane = tid & 63;
    const int wv   = tid >> 6;        // wave id 0..3
    const int quad = lane >> 4;       // 0..3
    const int l15  = lane & 15;
    const int bat  = blockIdx.x;
    const int R    = wv * 16;         // row base within batch

    // ---- x A-fragments (fp32 -> bf16). xa[t][j] = x[R+l15][t*32+quad*8+j]
    bf16x8 xa[8];
    {
        const float* xrow = x + ((size_t)bat * 64 + R + l15) * 256;
        #pragma unroll
        for (int t = 0; t < 8; ++t) {
            f32x4 lo = *(const f32x4*)(xrow + t * 32 + quad * 8);
            f32x4 hi = *(const f32x4*)(xrow + t * 32 + quad * 8 + 4);
            bf16x8 v;
            v[0] = (bf16_t)lo[0]; v[1] = (bf16_t)lo[1];
            v[2] = (bf16_t)lo[2]; v[3] = (bf16_t)lo[3];
            v[4] = (bf16_t)hi[0]; v[5] = (bf16_t)hi[1];
            v[6] = (bf16_t)hi[2]; v[7] = (bf16_t)hi[3];
            xa[t] = v;
        }
    }

    bf16x8 oa[8];   // out A-frags (layer-2/3 input)
    bf16x8 qa[8];   // q  A-frags (logits input)

    // ---------------- layer 1: out = relu(x@w1.T + b1) -> oa ----------------
    // Bulk transpose through the wave's 16-row slice of the swizzled buffer.
    {
        const bf16_t* wl = wf;
        #pragma unroll
        for (int n = 0; n < 16; ++n) {
            f32x4 acc = gemm_row16<USE_WS>(xa, wl, w1, n, lane);
            float bias = b1[n * 16 + l15];
            #pragma unroll
            for (int r2 = 0; r2 < 4; ++r2) {
                float v = fmaxf(acc[r2] + bias, 0.f);
                *(bf16_t*)(u_lds + ks_off(R + quad * 4 + r2, n * 16 + l15)) = (bf16_t)v;
            }
        }
        #pragma unroll
        for (int t = 0; t < 8; ++t)
            oa[t] = *(const bf16x8*)(u_lds + ks_off(R + l15, t * 32 + quad * 8));
    }

    // ---------------- layer 2: q = out@w2.T + b2 -> qa ----------------
    {
        const bf16_t* wl = wf + 65536;
        #pragma unroll
        for (int n = 0; n < 16; ++n) {
            f32x4 acc = gemm_row16<USE_WS>(oa, wl, w2, n, lane);
            float bias = b2[n * 16 + l15];
            #pragma unroll
            for (int r2 = 0; r2 < 4; ++r2)
                *(bf16_t*)(u_lds + ks_off(R + quad * 4 + r2, n * 16 + l15)) =
                    (bf16_t)(acc[r2] + bias);
        }
        #pragma unroll
        for (int t = 0; t < 8; ++t)
            qa[t] = *(const bf16x8*)(u_lds + ks_off(R + l15, t * 32 + quad * 8));
    }

    // ---------------- layer 3: k = out@w3.T + b3 -> ks (LDS) ----------------
    {
        const bf16_t* wl = wf + 2 * 65536;
        #pragma unroll
        for (int n = 0; n < 16; ++n) {
            f32x4 acc = gemm_row16<USE_WS>(oa, wl, w3, n, lane);
            float bias = b3[n * 16 + l15];
            #pragma unroll
            for (int r2 = 0; r2 < 4; ++r2)
                *(bf16_t*)(u_lds + ks_off(R + quad * 4 + r2, n * 16 + l15)) =
                    (bf16_t)(acc[r2] + bias);
        }
    }

    __syncthreads();   // #1: ks complete across all waves

    // ---------------- logits = q@k.T * SCALE -> registers -------------------
    f32x4 la[4];
    {
        #pragma unroll
        for (int n = 0; n < 4; ++n) {
            f32x4 acc = {0.f, 0.f, 0.f, 0.f};
            #pragma unroll
            for (int t = 0; t < 8; ++t) {
                bf16x8 kfr = *(const bf16x8*)(u_lds + ks_off(n * 16 + l15,
                                                             t * 32 + quad * 8));
                acc = __builtin_amdgcn_mfma_f32_16x16x32_bf16(qa[t], kfr, acc, 0, 0, 0);
            }
            la[n] = acc;
        }
    }

    // ---------------- promo offsets: offs[p][s] = k[56+s]·w4[p] -------------
    {
        int s = lane >> 3, seg = lane & 7;     // wave wv handles p = wv
        const float* wrow = w4 + wv * 256;
        float p = 0.f;
        #pragma unroll
        for (int m = 0; m < 8; ++m) {
            f32x4 w4v = *(const f32x4*)(wrow + seg * 32 + m * 4);
            #pragma unroll
            for (int j = 0; j < 4; ++j) {
                int h = seg * 32 + m * 4 + j;
                p += (float)(*(const bf16_t*)(u_lds + ks_off(56 + s, h))) * w4v[j];
            }
        }
        p += __shfl_down(p, 4);
        p += __shfl_down(p, 2);
        p += __shfl_down(p, 1);
        if (seg == 0) promoLDS[wv][s] = p;
    }

    // wave 3 stages the logits[48:56, 56:64] patch (rows 48-55 = quads 0,1)
    if (wv == 3 && quad < 2 && l15 >= 8) {
        #pragma unroll
        for (int r2 = 0; r2 < 4; ++r2)
            patchLDS[quad * 4 + r2][l15 - 8] = la[3][r2] * PSCALE;
    }

    __syncthreads();   // #2: everyone done READING ks; promoLDS/patch ready

    // ---------------- fullbuf (aliased over ks region) ----------------------
    float* fullbuf = (float*)u_lds;
    #pragma unroll
    for (int n = 0; n < 4; ++n) {
        #pragma unroll
        for (int r2 = 0; r2 < 4; ++r2)
            fullbuf[(R + quad * 4 + r2) * 64 + n * 16 + l15] = la[n][r2] * PSCALE;
    }

    // promo rows 64..66 (reads patchLDS/promoLDS only, no fullbuf dependency)
    if (tid < 192) {
        int u = tid >> 6, vv = tid & 63;
        int mm = u * 64 + vv;                  // flat 0..191 over (8 x 24)
        int r_ = mm / 24, c_ = mm - r_ * 24;
        int c3 = c_ / 3, cp = c_ - c3 * 3;     // c3 = s (0..7), cp = p (0..2)
        fullbuf[(64 + u) * 64 + vv] =
            promoLDS[cp][c3] + promoLDS[3][c3] + patchLDS[r_][c3];
    }

    __syncthreads();   // #3: fullbuf ready

    // ---------------- gather (batched: loads, then LDS reads, then stores) --
    {
        float* orow = out + (size_t)bat * NPOL;
        int   idxv[8];
        float valv[8];
        #pragma unroll
        for (int i = 0; i < 8; ++i) {
            int g = tid + i * 256;
            idxv[i] = (g < NPOL) ? gidx[g] : 0;
        }
        #pragma unroll
        for (int i = 0; i < 8; ++i)
            valv[i] = fullbuf[idxv[i]];
        #pragma unroll
        for (int i = 0; i < 8; ++i) {
            int g = tid + i * 256;
            if (g < NPOL) orow[g] = valv[i];
        }
    }
}

extern "C" void kernel_launch(void* const* d_in, const int* in_sizes, int n_in,
                              void* d_out, int out_size, void* d_ws, size_t ws_size,
                              hipStream_t stream) {
    const float* x    = (const float*)d_in[0];
    const float* w1   = (const float*)d_in[1];
    const float* b1   = (const float*)d_in[2];
    const float* w2   = (const float*)d_in[3];
    const float* b2   = (const float*)d_in[4];
    const float* w3   = (const float*)d_in[5];
    const float* b3   = (const float*)d_in[6];
    const float* w4   = (const float*)d_in[7];
    const int*   gidx = (const int*)d_in[8];
    float* out = (float*)d_out;
    bf16_t* wf = (bf16_t*)d_ws;                 // needs 3*65536 bf16 = 384 KB

    int nbat = in_sizes[0] / (64 * 256);        // 4096
    const size_t ws_needed = (size_t)3 * 65536 * sizeof(bf16_t);

    if (ws_size >= ws_needed) {
        prep_weights<<<768, 256, 0, stream>>>(w1, w2, w3, wf);
        policy_main<true><<<nbat, 256, 0, stream>>>(
            x, wf, w1, w2, w3, b1, b2, b3, w4, gidx, out);
    } else {
        policy_main<false><<<nbat, 256, 0, stream>>>(
            x, wf, w1, w2, w3, b1, b2, b3, w4, gidx, out);
    }
}